// Round 9
// baseline (289.633 us; speedup 1.0000x reference)
//
#include <hip/hip_runtime.h>
#include <hip/hip_bf16.h>
#include <math.h>

// Problem constants (fixed shapes)
#define BATCH   2
#define TSEQ    2048
#define DEMBED  1024
#define NHEAD   16
#define DHEAD   64
#define NGROUP  4
#define ROPEN   32
#define FQKV    1536          // (16 + 2*4) * 64
#define MROWS   (BATCH*TSEQ)  // 4096

typedef __attribute__((ext_vector_type(8))) short short8;   // 8 bf16 = 4 VGPR
typedef __attribute__((ext_vector_type(4))) float floatx4;  // MFMA C/D

// ---------------------------------------------------------------------------
// split helpers: f = hi + lo, hi = truncate-to-bf16(f), lo = bf16(f - hi).
// ---------------------------------------------------------------------------
__device__ __forceinline__ void split_pack8(const float* f, uint4& h4, uint4& l4) {
    uint u[8], lu[8];
    #pragma unroll
    for (int j = 0; j < 8; ++j) {
        u[j] = __float_as_uint(f[j]);
        float lf = f[j] - __uint_as_float(u[j] & 0xffff0000u);
        lu[j] = __float_as_uint(lf);
    }
    h4.x = __builtin_amdgcn_perm(u[1], u[0], 0x07060302u);
    h4.y = __builtin_amdgcn_perm(u[3], u[2], 0x07060302u);
    h4.z = __builtin_amdgcn_perm(u[5], u[4], 0x07060302u);
    h4.w = __builtin_amdgcn_perm(u[7], u[6], 0x07060302u);
    l4.x = __builtin_amdgcn_perm(lu[1], lu[0], 0x07060302u);
    l4.y = __builtin_amdgcn_perm(lu[3], lu[2], 0x07060302u);
    l4.z = __builtin_amdgcn_perm(lu[5], lu[4], 0x07060302u);
    l4.w = __builtin_amdgcn_perm(lu[7], lu[6], 0x07060302u);
}

__device__ __forceinline__ uint pack_hl(float p) {
    uint u = __float_as_uint(p);
    uint h = u & 0xffff0000u;
    float lf = p - __uint_as_float(h);
    return h | (__float_as_uint(lf) >> 16);
}

// async 16B/lane global->LDS copy; lds must be wave-uniform (HW adds lane*16)
__device__ __forceinline__ void lds_async16(void* lds, const void* gp) {
    __builtin_amdgcn_global_load_lds(
        (const __attribute__((address_space(1))) unsigned int*)gp,
        (__attribute__((address_space(3))) unsigned int*)lds,
        16, 0, 0);
}

// ===========================================================================
// MFMA-GEMM: pre-swizzled hi/lo bf16 images.
// Image layout (A and B^T): per (tile128, kblock64):
//   [hi: 128 rows x 128B][lo: 128 rows x 128B] = 32 KB, tile index = rt*16 + c.
//   Row r holds 64 bf16 k-values as 8 chunks of 16B; chunk j at phys j^(r&7).
// ===========================================================================

// ---- x converter: [4096][1024] f32 row-major -> A-image ----
__global__ __launch_bounds__(256) void conv_xy(const float* __restrict__ in,
                                               char* __restrict__ img) {
    const int tid = threadIdx.x;
    const int c   = blockIdx.x & 15;
    const int mt  = blockIdx.x >> 4;
    const int r    = tid >> 1;
    const int half = tid & 1;

    const float* src = in + (size_t)(mt*128 + r)*1024 + c*64 + half*32;
    float f[32];
    #pragma unroll
    for (int u = 0; u < 8; ++u)
        *(float4*)(f + 4*u) = *(const float4*)(src + 4*u);

    char* tile = img + ((size_t)(mt*16 + c)) * 32768;
    #pragma unroll
    for (int cc = 0; cc < 4; ++cc) {
        uint4 h4, l4;
        split_pack8(f + cc*8, h4, l4);
        int j    = half*4 + cc;
        int phys = j ^ (r & 7);
        *(uint4*)(tile + r*128 + phys*16)         = h4;
        *(uint4*)(tile + 16384 + r*128 + phys*16) = l4;
    }
}

// ---- weight converter (transpose): W [1024][N] f32 -> B^T image ----
__global__ __launch_bounds__(256) void conv_w(const float* __restrict__ W,
                                              int N,
                                              char* __restrict__ img) {
    __shared__ float Lf[64][132];
    const int tid = threadIdx.x;
    const int c   = blockIdx.x;
    const int nt  = blockIdx.y;

    {
        const int kk = tid >> 2;
        const int nc = (tid & 3) * 32;
        const float* src = W + (size_t)(c*64 + kk)*N + nt*128 + nc;
        #pragma unroll
        for (int u = 0; u < 8; ++u)
            *(float4*)(&Lf[kk][nc + 4*u]) = *(const float4*)(src + 4*u);
    }
    __syncthreads();

    char* tile = img + ((size_t)(nt*16 + c)) * 32768;
    #pragma unroll
    for (int rep = 0; rep < 4; ++rep) {
        int idx = rep*256 + tid;
        int n = idx & 127;
        int j = idx >> 7;
        float v[8];
        #pragma unroll
        for (int i = 0; i < 8; ++i) v[i] = Lf[j*8 + i][n];
        uint4 h4, l4;
        split_pack8(v, h4, l4);
        int phys = j ^ (n & 7);
        *(uint4*)(tile + n*128 + phys*16)         = h4;
        *(uint4*)(tile + 16384 + n*128 + phys*16) = l4;
    }
}

// ---- split-bf16 MFMA GEMM core: 128x128 tile, BK=64, 4 waves (2x2) ----
struct GemmAcc { floatx4 a[4][4]; };

__device__ __forceinline__ void gemm_mfma_core(const char* __restrict__ Aimg,
                                               const char* __restrict__ Bimg,
                                               char* smem, int mt, int nt,
                                               int tid, GemmAcc& G) {
    const int wv = tid >> 6;
    const int wm = wv & 1, wn = wv >> 1;
    const int lane = tid & 63;
    const int qd = lane >> 4, cl = lane & 15;

    #pragma unroll
    for (int tm = 0; tm < 4; ++tm)
        #pragma unroll
        for (int tn = 0; tn < 4; ++tn)
            G.a[tm][tn] = (floatx4){0.f, 0.f, 0.f, 0.f};

    for (int c = 0; c < 16; ++c) {
        __syncthreads();
        {
            const uint4* gA = (const uint4*)(Aimg + ((size_t)(mt*16 + c)) * 32768);
            const uint4* gB = (const uint4*)(Bimg + ((size_t)(nt*16 + c)) * 32768);
            uint4* lA = (uint4*)smem;
            uint4* lB = (uint4*)(smem + 32768);
            #pragma unroll
            for (int j = 0; j < 8; ++j) {
                lA[j*256 + tid] = gA[j*256 + tid];
                lB[j*256 + tid] = gB[j*256 + tid];
            }
        }
        __syncthreads();

        #pragma unroll
        for (int s = 0; s < 2; ++s) {
            const int phys = ((s*4 + qd) ^ (cl & 7)) * 16;
            short8 ah[4], al[4], bh[4], bl[4];
            #pragma unroll
            for (int tt = 0; tt < 4; ++tt) {
                const int rA = wm*64 + 16*tt + cl;
                ah[tt] = *(const short8*)(smem + rA*128 + phys);
                al[tt] = *(const short8*)(smem + 16384 + rA*128 + phys);
                const int rB = wn*64 + 16*tt + cl;
                bh[tt] = *(const short8*)(smem + 32768 + rB*128 + phys);
                bl[tt] = *(const short8*)(smem + 49152 + rB*128 + phys);
            }
            #pragma unroll
            for (int tm = 0; tm < 4; ++tm)
                #pragma unroll
                for (int tn = 0; tn < 4; ++tn) {
                    G.a[tm][tn] = __builtin_amdgcn_mfma_f32_16x16x32_bf16(ah[tm], bh[tn], G.a[tm][tn], 0, 0, 0);
                    G.a[tm][tn] = __builtin_amdgcn_mfma_f32_16x16x32_bf16(al[tm], bh[tn], G.a[tm][tn], 0, 0, 0);
                    G.a[tm][tn] = __builtin_amdgcn_mfma_f32_16x16x32_bf16(ah[tm], bl[tn], G.a[tm][tn], 0, 0, 0);
                }
        }
    }
}

// ---- qkv projection with fused RoPE + K/V image epilogue ----
__global__ __launch_bounds__(256, 2) void gemm_qkv_mfma(const char* __restrict__ Aimg,
                                                        const char* __restrict__ Bimg,
                                                        const float* __restrict__ cosp,
                                                        const float* __restrict__ sinp,
                                                        float* __restrict__ Qf,
                                                        ushort* __restrict__ Kimg,
                                                        ushort* __restrict__ Vimg) {
    __shared__ __align__(16) char smem[68608];   // main loop uses [0,65536)
    const int tid = threadIdx.x;
    const int nt = blockIdx.x, mt = blockIdx.y;

    GemmAcc G;
    gemm_mfma_core(Aimg, Bimg, smem, mt, nt, tid, G);

    const int wv = tid >> 6;
    const int wm = wv & 1, wn = wv >> 1;
    const int lane = tid & 63;
    const int qd = lane >> 4, cl = lane & 15;

    const int slice = nt*2 + wn;          // 0..23
    const int g  = slice / 6;
    const int jj = slice % 6;
    const int b  = mt >> 4;

    // ---- RoPE in C-fragment space (Q and K): dims cl (tn=0) & 16+cl (tn=1)
    if (jj != 5) {
        #pragma unroll
        for (int tm = 0; tm < 4; ++tm)
            #pragma unroll
            for (int r = 0; r < 4; ++r) {
                int m = mt*128 + wm*64 + 16*tm + 4*qd + r;
                int t = m & 2047;
                float c1 = cosp[t*ROPEN + cl],      s1 = sinp[t*ROPEN + cl];
                float c2 = cosp[t*ROPEN + 16 + cl], s2 = sinp[t*ROPEN + 16 + cl];
                float x1 = G.a[tm][0][r], x2 = G.a[tm][1][r];
                G.a[tm][0][r] = x1*c1 - x2*s1;
                G.a[tm][1][r] = x2*c2 + x1*s2;
            }
    }

    if (jj < 4) {
        #pragma unroll
        for (int tm = 0; tm < 4; ++tm)
            #pragma unroll
            for (int tn = 0; tn < 4; ++tn)
                #pragma unroll
                for (int r = 0; r < 4; ++r) {
                    int m = mt*128 + wm*64 + 16*tm + 4*qd + r;
                    Qf[(size_t)m*1024 + (g*4 + jj)*64 + 16*tn + cl] = G.a[tm][tn][r];
                }
    } else {
        // K/V: wave-private LDS transpose -> swizzled hi/lo image
        float* Lw = (float*)(smem + wv*17152);   // 64 x 67 f32
        __syncthreads();   // main-loop LDS reads complete (uniform: KV block)
        #pragma unroll
        for (int tm = 0; tm < 4; ++tm)
            #pragma unroll
            for (int tn = 0; tn < 4; ++tn)
                #pragma unroll
                for (int r = 0; r < 4; ++r)
                    Lw[(16*tm + 4*qd + r)*67 + 16*tn + cl] = G.a[tm][tn][r];
        __syncthreads();

        const int cloc = (mt & 15)*2 + wm;       // 64-key tile index within b
        ushort* img = ((jj == 4) ? Kimg : Vimg)
                      + (size_t)(b*4 + g)*262144 + (size_t)cloc*8192;
        if (jj == 4) {
            const int rr = lane;
            float f[8];
            #pragma unroll
            for (int ch = 0; ch < 8; ++ch) {
                *(float4*)f       = *(const float4*)(&Lw[rr*67 + ch*8]);
                *(float4*)(f + 4) = *(const float4*)(&Lw[rr*67 + ch*8 + 4]);
                uint4 h4, l4;
                split_pack8(f, h4, l4);
                int phys = ch ^ (rr & 7);
                *(uint4*)(img + rr*64 + phys*8)        = h4;
                *(uint4*)(img + 4096 + rr*64 + phys*8) = l4;
            }
        } else {
            const int d = lane;
            float f[8];
            #pragma unroll
            for (int ch = 0; ch < 8; ++ch) {
                #pragma unroll
                for (int i = 0; i < 8; ++i) f[i] = Lw[(ch*8 + i)*67 + d];
                uint4 h4, l4;
                split_pack8(f, h4, l4);
                int phys = ch ^ (d & 7);
                *(uint4*)(img + d*64 + phys*8)        = h4;
                *(uint4*)(img + 4096 + d*64 + phys*8) = l4;
            }
        }
    }
}

// ---- output projection: out = yb @ Wout ----
__global__ __launch_bounds__(256, 2) void gemm_out_mfma(const char* __restrict__ Aimg,
                                                        const char* __restrict__ Bimg,
                                                        float* __restrict__ C) {
    __shared__ __align__(16) char smem[65536];
    const int tid = threadIdx.x;
    const int nt = blockIdx.x, mt = blockIdx.y;

    GemmAcc G;
    gemm_mfma_core(Aimg, Bimg, smem, mt, nt, tid, G);

    const int wv = tid >> 6;
    const int wm = wv & 1, wn = wv >> 1;
    const int lane = tid & 63;
    const int qd = lane >> 4, cl = lane & 15;

    #pragma unroll
    for (int tm = 0; tm < 4; ++tm)
        #pragma unroll
        for (int tn = 0; tn < 4; ++tn)
            #pragma unroll
            for (int r = 0; r < 4; ++r) {
                int m = mt*128 + wm*64 + 16*tm + 4*qd + r;
                int n = nt*128 + wn*64 + 16*tn + cl;
                C[(size_t)m*1024 + n] = G.a[tm][tn][r];
            }
}

// ---------------------------------------------------------------------------
// MFMA flash attention v5 — key-split partials.
// Block = (bg, hj, qt, kh): 128 q-rows x 1024 keys (kh half).  Grid 1024 ->
// 3 blocks/CU co-resident (LDS 51200) for pipe overlap.  Writes UNNORMALIZED
// partial O (fp32, [dest][row][dim]) + per-row partial l; combine kernel sums.
// ---------------------------------------------------------------------------
__global__ __launch_bounds__(256, 3) void attn5(const float* __restrict__ Qf,
                                                const uint4* __restrict__ Kimg,
                                                const uint4* __restrict__ Vimg,
                                                float* __restrict__ Opart,
                                                float* __restrict__ Lpart) {
    __shared__ __align__(16) char smem[51200];
    char* Kl = smem;
    char* Vl = smem + 16384;
    uint* Pp = (uint*)(smem + 32768);        // 128 rows x stride 36 uints

    const int tid  = threadIdx.x;
    const int wv   = tid >> 6;
    const int lane = tid & 63;
    const int qd   = lane >> 4;
    const int cl   = lane & 15;

    const int bg    = blockIdx.x & 7;        // XCD-aligned
    const int inner = blockIdx.x >> 3;       // 0..127: hj(2) qt(4) kh(1)
    const int kh    = inner & 1;
    const int qt    = (inner >> 1) & 15;
    const int hj    = inner >> 5;
    const int b = bg >> 2, g = bg & 3;
    const int h = g*4 + hj;
    const int dest = (b*16 + qt)*16 + h;     // matches gemm_out tile index

    // ---- Q fragments -> registers, pre-scaled by 1/8 (exact) ----
    short8 qh[2][2], ql[2][2];
    #pragma unroll
    for (int rb = 0; rb < 2; ++rb) {
        const float* qp = Qf + (size_t)(b*2048 + qt*128 + 32*wv + 16*rb + cl)*1024
                             + h*64 + 8*qd;
        #pragma unroll
        for (int s = 0; s < 2; ++s) {
            float f[8];
            *(float4*)f       = *(const float4*)(qp + 32*s);
            *(float4*)(f + 4) = *(const float4*)(qp + 32*s + 4);
            #pragma unroll
            for (int i = 0; i < 8; ++i) f[i] *= 0.125f;
            uint4 h4, l4;
            split_pack8(f, h4, l4);
            qh[rb][s] = __builtin_bit_cast(short8, h4);
            ql[rb][s] = __builtin_bit_cast(short8, l4);
        }
    }

    floatx4 accO[2][4] = {};
    float lsum[2][4] = {};

    const uint4* gk0 = Kimg + (size_t)bg*32768;
    const uint4* gv0 = Vimg + (size_t)bg*32768;

    for (int c = kh*16; c < kh*16 + 16; ++c) {
        __syncthreads();
        {
            const uint4* gk = gk0 + c*1024 + tid;
            const uint4* gv = gv0 + c*1024 + tid;
            const int wslot = (tid & 192) * 16;
            #pragma unroll
            for (int j = 0; j < 4; ++j) {
                lds_async16(Kl + j*4096 + wslot, gk + j*256);
                lds_async16(Vl + j*4096 + wslot, gv + j*256);
            }
        }
        __syncthreads();

        // ---- S = Q.K^T (scores pre-scaled via Q) ----
        floatx4 accS[2][4] = {};
        #pragma unroll
        for (int s = 0; s < 2; ++s) {
            #pragma unroll
            for (int tt = 0; tt < 4; ++tt) {
                const int off = (16*tt + cl)*128 + (((4*s + qd) ^ (cl & 7))*16);
                short8 bh = *(const short8*)(Kl + off);
                short8 bl = *(const short8*)(Kl + 8192 + off);
                #pragma unroll
                for (int rb = 0; rb < 2; ++rb) {
                    accS[rb][tt] = __builtin_amdgcn_mfma_f32_16x16x32_bf16(qh[rb][s], bh, accS[rb][tt], 0, 0, 0);
                    accS[rb][tt] = __builtin_amdgcn_mfma_f32_16x16x32_bf16(ql[rb][s], bh, accS[rb][tt], 0, 0, 0);
                    accS[rb][tt] = __builtin_amdgcn_mfma_f32_16x16x32_bf16(qh[rb][s], bl, accS[rb][tt], 0, 0, 0);
                }
            }
        }

        // ---- softmax + PV in 2 key-half passes (P half-buffer) ----
        #pragma unroll
        for (int s = 0; s < 2; ++s) {
            #pragma unroll
            for (int rb = 0; rb < 2; ++rb)
                #pragma unroll
                for (int r = 0; r < 4; ++r) {
                    float p0 = __expf(accS[rb][2*s    ][r]);
                    float p1 = __expf(accS[rb][2*s + 1][r]);
                    lsum[rb][r] += p0 + p1;
                    uint* prow = Pp + (32*wv + 16*rb + 4*qd + r)*36 + cl;
                    prow[0]  = pack_hl(p0);
                    prow[16] = pack_hl(p1);
                }
            short8 pah[2], pal[2];
            #pragma unroll
            for (int rb = 0; rb < 2; ++rb) {
                const uint* pr = Pp + (32*wv + 16*rb + cl)*36 + 8*qd;
                uint4 da = *(const uint4*)(pr);
                uint4 db = *(const uint4*)(pr + 4);
                uint4 ph, pl;
                ph.x = __builtin_amdgcn_perm(da.y, da.x, 0x07060302u);
                ph.y = __builtin_amdgcn_perm(da.w, da.z, 0x07060302u);
                ph.z = __builtin_amdgcn_perm(db.y, db.x, 0x07060302u);
                ph.w = __builtin_amdgcn_perm(db.w, db.z, 0x07060302u);
                pl.x = __builtin_amdgcn_perm(da.y, da.x, 0x05040100u);
                pl.y = __builtin_amdgcn_perm(da.w, da.z, 0x05040100u);
                pl.z = __builtin_amdgcn_perm(db.y, db.x, 0x05040100u);
                pl.w = __builtin_amdgcn_perm(db.w, db.z, 0x05040100u);
                pah[rb] = __builtin_bit_cast(short8, ph);
                pal[rb] = __builtin_bit_cast(short8, pl);
            }
            #pragma unroll
            for (int tt = 0; tt < 4; ++tt) {
                const int off = (16*tt + cl)*128 + (((4*s + qd) ^ (cl & 7))*16);
                short8 vh  = *(const short8*)(Vl + off);
                short8 vl8 = *(const short8*)(Vl + 8192 + off);
                #pragma unroll
                for (int rb = 0; rb < 2; ++rb) {
                    accO[rb][tt] = __builtin_amdgcn_mfma_f32_16x16x32_bf16(pah[rb], vh,  accO[rb][tt], 0, 0, 0);
                    accO[rb][tt] = __builtin_amdgcn_mfma_f32_16x16x32_bf16(pal[rb], vh,  accO[rb][tt], 0, 0, 0);
                    accO[rb][tt] = __builtin_amdgcn_mfma_f32_16x16x32_bf16(pah[rb], vl8, accO[rb][tt], 0, 0, 0);
                }
            }
        }
    }

    // ---- epilogue: store unnormalized partials (no LDS needed) ----
    float* Op = Opart + (size_t)kh*4194304 + (size_t)dest*8192;
    float* Lp = Lpart + (size_t)kh*65536   + (size_t)dest*128;
    #pragma unroll
    for (int rb = 0; rb < 2; ++rb)
        #pragma unroll
        for (int r = 0; r < 4; ++r) {
            float l = lsum[rb][r];
            l += __shfl_xor(l, 1);
            l += __shfl_xor(l, 2);
            l += __shfl_xor(l, 4);
            l += __shfl_xor(l, 8);
            int row = 32*wv + 16*rb + 4*qd + r;
            if (cl == 0) Lp[row] = l;
            #pragma unroll
            for (int tt = 0; tt < 4; ++tt)
                Op[row*64 + 16*tt + cl] = accO[rb][tt][r];
        }
}

// ---------------------------------------------------------------------------
// combine: sum the two key-half partials, normalize, build the y hi/lo
// A-image tile IN PLACE over partial-0 (read-all -> barrier -> write-all).
// ---------------------------------------------------------------------------
__global__ __launch_bounds__(256) void combine(float* __restrict__ Opart,
                                               const float* __restrict__ Lpart,
                                               char* __restrict__ Yimg) {
    const int tid = threadIdx.x;
    const int bgc = blockIdx.x & 7;          // XCD-match with attn5 writers
    const int rest = blockIdx.x >> 3;        // 0..63: hj(2) qt(4)
    const int hj = rest & 3;
    const int qt = rest >> 2;
    const int b = bgc >> 2, g = bgc & 3;
    const int h = g*4 + hj;
    const int dest = (b*16 + qt)*16 + h;

    const int r0   = tid >> 1;               // row 0..127
    const int half = tid & 1;

    const float* O0 = Opart + (size_t)dest*8192 + r0*64 + half*32;
    const float* O1 = Opart + 4194304 + (size_t)dest*8192 + r0*64 + half*32;
    float l0 = Lpart[(size_t)dest*128 + r0];
    float l1 = Lpart[65536 + (size_t)dest*128 + r0];
    float inv = 1.0f / (l0 + l1);

    float f[32];
    #pragma unroll
    for (int u = 0; u < 8; ++u) {
        float4 a = *(const float4*)(O0 + 4*u);
        float4 c = *(const float4*)(O1 + 4*u);
        f[4*u+0] = (a.x + c.x) * inv;
        f[4*u+1] = (a.y + c.y) * inv;
        f[4*u+2] = (a.z + c.z) * inv;
        f[4*u+3] = (a.w + c.w) * inv;
    }
    __syncthreads();   // all partial-0 reads complete before in-place write

    char* tile = Yimg + (size_t)dest * 32768;
    #pragma unroll
    for (int cc = 0; cc < 4; ++cc) {
        uint4 h4, l4;
        split_pack8(f + 8*cc, h4, l4);
        int j    = half*4 + cc;
        int phys = j ^ (r0 & 7);
        *(uint4*)(tile + r0*128 + phys*16)         = h4;
        *(uint4*)(tile + 16384 + r0*128 + phys*16) = l4;
    }
}

// ---------------------------------------------------------------------------
extern "C" void kernel_launch(void* const* d_in, const int* in_sizes, int n_in,
                              void* d_out, int out_size, void* d_ws, size_t ws_size,
                              hipStream_t stream) {
    const float* x    = (const float*)d_in[0];
    const float* cosp = (const float*)d_in[1];
    const float* sinp = (const float*)d_in[2];
    // d_in[3] = mask: unused by the reference computation
    const float* Wqkv = (const float*)d_in[4];
    const float* Wout = (const float*)d_in[5];
    float* out = (float*)d_out;

    char* ws = (char*)d_ws;
    // Layout (bytes), total 61 MB — regions reused across pipeline phases:
    float*  Qf    = (float*)(ws);                      // [ 0,16M)
    ushort* Kimg  = (ushort*)(ws + ((size_t)16<<20));  // [16,20M)
    ushort* Vimg  = (ushort*)(ws + ((size_t)20<<20));  // [20,24M)
    char*   Bo    = ws + ((size_t)24<<20);             // [24,28M)
    char*   Ximg  = ws + ((size_t)28<<20);             // [28,44M)  (dead after qkv-gemm)
    char*   Bq    = ws + ((size_t)44<<20);             // [44,50M)  (dead after qkv-gemm)
    float*  Opart = (float*)(ws + ((size_t)28<<20));   // [28,60M)  partials (over Ximg/Bq/free)
    float*  Lpart = (float*)(ws + ((size_t)60<<20));   // [60,61M)
    char*   Yimg  = ws + ((size_t)28<<20);             // [28,44M)  (over partial-0, in place)

    // 1) input + weight images
    conv_xy<<<512, 256, 0, stream>>>(x, Ximg);
    conv_w<<<dim3(16, 12), 256, 0, stream>>>(Wqkv, FQKV, Bq);
    conv_w<<<dim3(16, 8), 256, 0, stream>>>(Wout, DEMBED, Bo);
    // 2) qkv projection + fused RoPE + K/V image build
    gemm_qkv_mfma<<<dim3(12, 32), 256, 0, stream>>>(Ximg, Bq, cosp, sinp,
                                                    Qf, Kimg, Vimg);
    // 3) attention, key-split partials (1024 blocks -> 3 blocks/CU overlap)
    attn5<<<1024, 256, 0, stream>>>(Qf, (const uint4*)Kimg, (const uint4*)Vimg,
                                    Opart, Lpart);
    // 3b) combine halves -> y image (in place over partial-0)
    combine<<<512, 256, 0, stream>>>(Opart, Lpart, Yimg);
    // 4) out = y @ Wout
    gemm_out_mfma<<<dim3(8, 32), 256, 0, stream>>>(Yimg, Bo, out);
}

// Round 10
// 270.511 us; speedup vs baseline: 1.0707x; 1.0707x over previous
//
#include <hip/hip_runtime.h>
#include <hip/hip_bf16.h>
#include <math.h>

// Problem constants (fixed shapes)
#define BATCH   2
#define TSEQ    2048
#define DEMBED  1024
#define NHEAD   16
#define DHEAD   64
#define NGROUP  4
#define ROPEN   32
#define FQKV    1536          // (16 + 2*4) * 64
#define MROWS   (BATCH*TSEQ)  // 4096

typedef __attribute__((ext_vector_type(8))) short short8;   // 8 bf16 = 4 VGPR
typedef __attribute__((ext_vector_type(4))) float floatx4;  // MFMA C/D

// ---------------------------------------------------------------------------
// split helpers: f = hi + lo, hi = truncate-to-bf16(f), lo = bf16(f - hi).
// ---------------------------------------------------------------------------
__device__ __forceinline__ void split_pack8(const float* f, uint4& h4, uint4& l4) {
    uint u[8], lu[8];
    #pragma unroll
    for (int j = 0; j < 8; ++j) {
        u[j] = __float_as_uint(f[j]);
        float lf = f[j] - __uint_as_float(u[j] & 0xffff0000u);
        lu[j] = __float_as_uint(lf);
    }
    h4.x = __builtin_amdgcn_perm(u[1], u[0], 0x07060302u);
    h4.y = __builtin_amdgcn_perm(u[3], u[2], 0x07060302u);
    h4.z = __builtin_amdgcn_perm(u[5], u[4], 0x07060302u);
    h4.w = __builtin_amdgcn_perm(u[7], u[6], 0x07060302u);
    l4.x = __builtin_amdgcn_perm(lu[1], lu[0], 0x07060302u);
    l4.y = __builtin_amdgcn_perm(lu[3], lu[2], 0x07060302u);
    l4.z = __builtin_amdgcn_perm(lu[5], lu[4], 0x07060302u);
    l4.w = __builtin_amdgcn_perm(lu[7], lu[6], 0x07060302u);
}

// round-to-nearest bf16 pack of 8 floats -> hi-only uint4 (unbiased)
__device__ __forceinline__ void rtn_pack8(const float* f, uint4& h4) {
    uint t[8];
    #pragma unroll
    for (int j = 0; j < 8; ++j)
        t[j] = __float_as_uint(f[j]) + 0x8000u;
    h4.x = __builtin_amdgcn_perm(t[1], t[0], 0x07060302u);
    h4.y = __builtin_amdgcn_perm(t[3], t[2], 0x07060302u);
    h4.z = __builtin_amdgcn_perm(t[5], t[4], 0x07060302u);
    h4.w = __builtin_amdgcn_perm(t[7], t[6], 0x07060302u);
}

__device__ __forceinline__ ushort bf16_rtn(float x) {
    return (ushort)((__float_as_uint(x) + 0x8000u) >> 16);
}

// async 16B/lane global->LDS copy; lds must be wave-uniform (HW adds lane*16)
__device__ __forceinline__ void lds_async16(void* lds, const void* gp) {
    __builtin_amdgcn_global_load_lds(
        (const __attribute__((address_space(1))) unsigned int*)gp,
        (__attribute__((address_space(3))) unsigned int*)lds,
        16, 0, 0);
}

// ===========================================================================
// MFMA-GEMM: pre-swizzled hi/lo bf16 images.
// Image layout (A and B^T): per (tile128, kblock64):
//   [hi: 128 rows x 128B][lo: 128 rows x 128B] = 32 KB, tile index = rt*16 + c.
//   Row r holds 64 bf16 k-values as 8 chunks of 16B; chunk j at phys j^(r&7).
// ===========================================================================

// ---- x converter: [4096][1024] f32 row-major -> A-image ----
__global__ __launch_bounds__(256) void conv_xy(const float* __restrict__ in,
                                               char* __restrict__ img) {
    const int tid = threadIdx.x;
    const int c   = blockIdx.x & 15;
    const int mt  = blockIdx.x >> 4;
    const int r    = tid >> 1;
    const int half = tid & 1;

    const float* src = in + (size_t)(mt*128 + r)*1024 + c*64 + half*32;
    float f[32];
    #pragma unroll
    for (int u = 0; u < 8; ++u)
        *(float4*)(f + 4*u) = *(const float4*)(src + 4*u);

    char* tile = img + ((size_t)(mt*16 + c)) * 32768;
    #pragma unroll
    for (int cc = 0; cc < 4; ++cc) {
        uint4 h4, l4;
        split_pack8(f + cc*8, h4, l4);
        int j    = half*4 + cc;
        int phys = j ^ (r & 7);
        *(uint4*)(tile + r*128 + phys*16)         = h4;
        *(uint4*)(tile + 16384 + r*128 + phys*16) = l4;
    }
}

// ---- weight converter (transpose): W [1024][N] f32 -> B^T image ----
__global__ __launch_bounds__(256) void conv_w(const float* __restrict__ W,
                                              int N,
                                              char* __restrict__ img) {
    __shared__ float Lf[64][132];
    const int tid = threadIdx.x;
    const int c   = blockIdx.x;
    const int nt  = blockIdx.y;

    {
        const int kk = tid >> 2;
        const int nc = (tid & 3) * 32;
        const float* src = W + (size_t)(c*64 + kk)*N + nt*128 + nc;
        #pragma unroll
        for (int u = 0; u < 8; ++u)
            *(float4*)(&Lf[kk][nc + 4*u]) = *(const float4*)(src + 4*u);
    }
    __syncthreads();

    char* tile = img + ((size_t)(nt*16 + c)) * 32768;
    #pragma unroll
    for (int rep = 0; rep < 4; ++rep) {
        int idx = rep*256 + tid;
        int n = idx & 127;
        int j = idx >> 7;
        float v[8];
        #pragma unroll
        for (int i = 0; i < 8; ++i) v[i] = Lf[j*8 + i][n];
        uint4 h4, l4;
        split_pack8(v, h4, l4);
        int phys = j ^ (n & 7);
        *(uint4*)(tile + n*128 + phys*16)         = h4;
        *(uint4*)(tile + 16384 + n*128 + phys*16) = l4;
    }
}

// ---- split-bf16 MFMA GEMM core: 128x128 tile, BK=64, 4 waves (2x2) ----
struct GemmAcc { floatx4 a[4][4]; };

__device__ __forceinline__ void gemm_mfma_core(const char* __restrict__ Aimg,
                                               const char* __restrict__ Bimg,
                                               char* smem, int mt, int nt,
                                               int tid, GemmAcc& G) {
    const int wv = tid >> 6;
    const int wm = wv & 1, wn = wv >> 1;
    const int lane = tid & 63;
    const int qd = lane >> 4, cl = lane & 15;

    #pragma unroll
    for (int tm = 0; tm < 4; ++tm)
        #pragma unroll
        for (int tn = 0; tn < 4; ++tn)
            G.a[tm][tn] = (floatx4){0.f, 0.f, 0.f, 0.f};

    for (int c = 0; c < 16; ++c) {
        __syncthreads();
        {
            const uint4* gA = (const uint4*)(Aimg + ((size_t)(mt*16 + c)) * 32768);
            const uint4* gB = (const uint4*)(Bimg + ((size_t)(nt*16 + c)) * 32768);
            uint4* lA = (uint4*)smem;
            uint4* lB = (uint4*)(smem + 32768);
            #pragma unroll
            for (int j = 0; j < 8; ++j) {
                lA[j*256 + tid] = gA[j*256 + tid];
                lB[j*256 + tid] = gB[j*256 + tid];
            }
        }
        __syncthreads();

        #pragma unroll
        for (int s = 0; s < 2; ++s) {
            const int phys = ((s*4 + qd) ^ (cl & 7)) * 16;
            short8 ah[4], al[4], bh[4], bl[4];
            #pragma unroll
            for (int tt = 0; tt < 4; ++tt) {
                const int rA = wm*64 + 16*tt + cl;
                ah[tt] = *(const short8*)(smem + rA*128 + phys);
                al[tt] = *(const short8*)(smem + 16384 + rA*128 + phys);
                const int rB = wn*64 + 16*tt + cl;
                bh[tt] = *(const short8*)(smem + 32768 + rB*128 + phys);
                bl[tt] = *(const short8*)(smem + 49152 + rB*128 + phys);
            }
            #pragma unroll
            for (int tm = 0; tm < 4; ++tm)
                #pragma unroll
                for (int tn = 0; tn < 4; ++tn) {
                    G.a[tm][tn] = __builtin_amdgcn_mfma_f32_16x16x32_bf16(ah[tm], bh[tn], G.a[tm][tn], 0, 0, 0);
                    G.a[tm][tn] = __builtin_amdgcn_mfma_f32_16x16x32_bf16(al[tm], bh[tn], G.a[tm][tn], 0, 0, 0);
                    G.a[tm][tn] = __builtin_amdgcn_mfma_f32_16x16x32_bf16(ah[tm], bl[tn], G.a[tm][tn], 0, 0, 0);
                }
        }
    }
}

// ---- qkv projection with fused RoPE + K/V image epilogue ----
__global__ __launch_bounds__(256, 2) void gemm_qkv_mfma(const char* __restrict__ Aimg,
                                                        const char* __restrict__ Bimg,
                                                        const float* __restrict__ cosp,
                                                        const float* __restrict__ sinp,
                                                        float* __restrict__ Qf,
                                                        ushort* __restrict__ Kimg,
                                                        ushort* __restrict__ Vimg) {
    __shared__ __align__(16) char smem[68608];   // main loop uses [0,65536)
    const int tid = threadIdx.x;
    const int nt = blockIdx.x, mt = blockIdx.y;

    GemmAcc G;
    gemm_mfma_core(Aimg, Bimg, smem, mt, nt, tid, G);

    const int wv = tid >> 6;
    const int wm = wv & 1, wn = wv >> 1;
    const int lane = tid & 63;
    const int qd = lane >> 4, cl = lane & 15;

    const int slice = nt*2 + wn;          // 0..23
    const int g  = slice / 6;
    const int jj = slice % 6;
    const int b  = mt >> 4;

    // ---- RoPE in C-fragment space (Q and K): dims cl (tn=0) & 16+cl (tn=1)
    if (jj != 5) {
        #pragma unroll
        for (int tm = 0; tm < 4; ++tm)
            #pragma unroll
            for (int r = 0; r < 4; ++r) {
                int m = mt*128 + wm*64 + 16*tm + 4*qd + r;
                int t = m & 2047;
                float c1 = cosp[t*ROPEN + cl],      s1 = sinp[t*ROPEN + cl];
                float c2 = cosp[t*ROPEN + 16 + cl], s2 = sinp[t*ROPEN + 16 + cl];
                float x1 = G.a[tm][0][r], x2 = G.a[tm][1][r];
                G.a[tm][0][r] = x1*c1 - x2*s1;
                G.a[tm][1][r] = x2*c2 + x1*s2;
            }
    }

    if (jj < 4) {
        #pragma unroll
        for (int tm = 0; tm < 4; ++tm)
            #pragma unroll
            for (int tn = 0; tn < 4; ++tn)
                #pragma unroll
                for (int r = 0; r < 4; ++r) {
                    int m = mt*128 + wm*64 + 16*tm + 4*qd + r;
                    Qf[(size_t)m*1024 + (g*4 + jj)*64 + 16*tn + cl] = G.a[tm][tn][r];
                }
    } else {
        // K/V: wave-private LDS transpose -> swizzled image
        // K: exact hi/lo split (truncate).  V: RTN hi only (attn uses hi only).
        float* Lw = (float*)(smem + wv*17152);   // 64 x 67 f32
        __syncthreads();   // main-loop LDS reads complete (uniform: KV block)
        #pragma unroll
        for (int tm = 0; tm < 4; ++tm)
            #pragma unroll
            for (int tn = 0; tn < 4; ++tn)
                #pragma unroll
                for (int r = 0; r < 4; ++r)
                    Lw[(16*tm + 4*qd + r)*67 + 16*tn + cl] = G.a[tm][tn][r];
        __syncthreads();

        const int cloc = (mt & 15)*2 + wm;       // 64-key tile index within b
        ushort* img = ((jj == 4) ? Kimg : Vimg)
                      + (size_t)(b*4 + g)*262144 + (size_t)cloc*8192;
        if (jj == 4) {
            const int rr = lane;
            float f[8];
            #pragma unroll
            for (int ch = 0; ch < 8; ++ch) {
                *(float4*)f       = *(const float4*)(&Lw[rr*67 + ch*8]);
                *(float4*)(f + 4) = *(const float4*)(&Lw[rr*67 + ch*8 + 4]);
                uint4 h4, l4;
                split_pack8(f, h4, l4);
                int phys = ch ^ (rr & 7);
                *(uint4*)(img + rr*64 + phys*8)        = h4;
                *(uint4*)(img + 4096 + rr*64 + phys*8) = l4;
            }
        } else {
            const int d = lane;
            float f[8];
            #pragma unroll
            for (int ch = 0; ch < 8; ++ch) {
                #pragma unroll
                for (int i = 0; i < 8; ++i) f[i] = Lw[(ch*8 + i)*67 + d];
                uint4 h4;
                rtn_pack8(f, h4);
                int phys = ch ^ (d & 7);
                *(uint4*)(img + d*64 + phys*8) = h4;   // hi only
            }
        }
    }
}

// ---- output projection: out = yb @ Wout ----
__global__ __launch_bounds__(256, 2) void gemm_out_mfma(const char* __restrict__ Aimg,
                                                        const char* __restrict__ Bimg,
                                                        float* __restrict__ C) {
    __shared__ __align__(16) char smem[65536];
    const int tid = threadIdx.x;
    const int nt = blockIdx.x, mt = blockIdx.y;

    GemmAcc G;
    gemm_mfma_core(Aimg, Bimg, smem, mt, nt, tid, G);

    const int wv = tid >> 6;
    const int wm = wv & 1, wn = wv >> 1;
    const int lane = tid & 63;
    const int qd = lane >> 4, cl = lane & 15;

    #pragma unroll
    for (int tm = 0; tm < 4; ++tm)
        #pragma unroll
        for (int tn = 0; tn < 4; ++tn)
            #pragma unroll
            for (int r = 0; r < 4; ++r) {
                int m = mt*128 + wm*64 + 16*tm + 4*qd + r;
                int n = nt*128 + wn*64 + 16*tn + cl;
                C[(size_t)m*1024 + n] = G.a[tm][tn][r];
            }
}

// ---------------------------------------------------------------------------
// MFMA flash attention v6.  Block = 128 q-rows of one (b,h), all 2048 keys.
// Double-buffered K (hi+lo) / V (hi only, RTN) staging via global_load_lds,
// ONE barrier per 64-key tile (prefetch c+1 issued after the barrier that
// publishes c; compute overlaps the flight).  S = 3-pass split bf16 MFMA;
// softmax exp; P stored as plain RTN bf16 (no lo, no unpack); PV single-pass.
// LDS: K dbuf 32K | V dbuf 16K | P 128x68 ushorts 17.4K = 66560 -> 2 blk/CU.
// Epilogue writes the hi/lo y A-image tile directly.
// ---------------------------------------------------------------------------
__global__ __launch_bounds__(256, 2) void attn6(const float* __restrict__ Qf,
                                                const uint4* __restrict__ Kimg,
                                                const uint4* __restrict__ Vimg,
                                                char* __restrict__ Yimg) {
    __shared__ __align__(16) char smem[66560];
    // K buffers at 0 / 16384; V buffers at 32768 / 40960; P at 49152
    ushort* Pp = (ushort*)(smem + 49152);    // 128 rows x stride 68 ushorts

    const int tid  = threadIdx.x;
    const int wv   = tid >> 6;
    const int lane = tid & 63;
    const int qd   = lane >> 4;
    const int cl   = lane & 15;

    const int bg    = blockIdx.x & 7;        // XCD-aligned
    const int inner = blockIdx.x >> 3;
    const int hj    = inner >> 4;            // head within group
    const int qt    = inner & 15;            // 128-row q tile
    const int b = bg >> 2, g = bg & 3;
    const int h = g*4 + hj;

    // ---- Q fragments -> registers, pre-scaled by 1/8 (exact) ----
    short8 qh[2][2], ql[2][2];
    #pragma unroll
    for (int rb = 0; rb < 2; ++rb) {
        const float* qp = Qf + (size_t)(b*2048 + qt*128 + 32*wv + 16*rb + cl)*1024
                             + h*64 + 8*qd;
        #pragma unroll
        for (int s = 0; s < 2; ++s) {
            float f[8];
            *(float4*)f       = *(const float4*)(qp + 32*s);
            *(float4*)(f + 4) = *(const float4*)(qp + 32*s + 4);
            #pragma unroll
            for (int i = 0; i < 8; ++i) f[i] *= 0.125f;
            uint4 h4, l4;
            split_pack8(f, h4, l4);
            qh[rb][s] = __builtin_bit_cast(short8, h4);
            ql[rb][s] = __builtin_bit_cast(short8, l4);
        }
    }

    floatx4 accO[2][4] = {};
    float lsum[2][4] = {};

    const uint4* gk0 = Kimg + (size_t)bg*32768;
    const uint4* gv0 = Vimg + (size_t)bg*32768;
    const int wslot = (tid & 192) * 16;      // wave-uniform LDS byte offset

    // prefetch tile 0 into buffer 0
    {
        const uint4* gk = gk0 + tid;
        const uint4* gv = gv0 + tid;
        #pragma unroll
        for (int j = 0; j < 4; ++j)
            lds_async16(smem + j*4096 + wslot, gk + j*256);
        #pragma unroll
        for (int j = 0; j < 2; ++j)
            lds_async16(smem + 32768 + j*4096 + wslot, gv + j*256);
    }

    for (int c = 0; c < TSEQ/64; ++c) {
        __syncthreads();   // publishes tile c (drains vmcnt); reads of c-1 done
        const int buf = c & 1;
        if (c + 1 < TSEQ/64) {
            const int nb = (c + 1) & 1;
            const uint4* gk = gk0 + (c+1)*1024 + tid;
            const uint4* gv = gv0 + (c+1)*1024 + tid;
            #pragma unroll
            for (int j = 0; j < 4; ++j)
                lds_async16(smem + nb*16384 + j*4096 + wslot, gk + j*256);
            #pragma unroll
            for (int j = 0; j < 2; ++j)
                lds_async16(smem + 32768 + nb*8192 + j*4096 + wslot, gv + j*256);
        }
        char* Kl = smem + buf*16384;
        char* Vl = smem + 32768 + buf*8192;

        // ---- S = Q.K^T (scores pre-scaled via Q; 3-pass split) ----
        floatx4 accS[2][4] = {};
        #pragma unroll
        for (int s = 0; s < 2; ++s) {
            #pragma unroll
            for (int tt = 0; tt < 4; ++tt) {
                const int off = (16*tt + cl)*128 + (((4*s + qd) ^ (cl & 7))*16);
                short8 bh = *(const short8*)(Kl + off);
                short8 bl = *(const short8*)(Kl + 8192 + off);
                #pragma unroll
                for (int rb = 0; rb < 2; ++rb) {
                    accS[rb][tt] = __builtin_amdgcn_mfma_f32_16x16x32_bf16(qh[rb][s], bh, accS[rb][tt], 0, 0, 0);
                    accS[rb][tt] = __builtin_amdgcn_mfma_f32_16x16x32_bf16(ql[rb][s], bh, accS[rb][tt], 0, 0, 0);
                    accS[rb][tt] = __builtin_amdgcn_mfma_f32_16x16x32_bf16(qh[rb][s], bl, accS[rb][tt], 0, 0, 0);
                }
            }
        }

        // ---- softmax: exp, P as RTN bf16 (wave-private rows, no barrier) ----
        #pragma unroll
        for (int rb = 0; rb < 2; ++rb)
            #pragma unroll
            for (int r = 0; r < 4; ++r) {
                float p0 = __expf(accS[rb][0][r]);
                float p1 = __expf(accS[rb][1][r]);
                float p2 = __expf(accS[rb][2][r]);
                float p3 = __expf(accS[rb][3][r]);
                lsum[rb][r] += (p0 + p1) + (p2 + p3);
                ushort* prow = Pp + (32*wv + 16*rb + 4*qd + r)*68 + cl;
                prow[0]  = bf16_rtn(p0);
                prow[16] = bf16_rtn(p1);
                prow[32] = bf16_rtn(p2);
                prow[48] = bf16_rtn(p3);
            }

        // ---- O += P.V : single pass, P read directly as bf16 A-frags ----
        #pragma unroll
        for (int s = 0; s < 2; ++s) {
            short8 pa[2];
            #pragma unroll
            for (int rb = 0; rb < 2; ++rb)
                pa[rb] = *(const short8*)(Pp + (32*wv + 16*rb + cl)*68 + 32*s + 8*qd);
            #pragma unroll
            for (int tt = 0; tt < 4; ++tt) {
                const int off = (16*tt + cl)*128 + (((4*s + qd) ^ (cl & 7))*16);
                short8 vh = *(const short8*)(Vl + off);
                #pragma unroll
                for (int rb = 0; rb < 2; ++rb)
                    accO[rb][tt] = __builtin_amdgcn_mfma_f32_16x16x32_bf16(pa[rb], vh, accO[rb][tt], 0, 0, 0);
            }
        }
    }

    // ---- epilogue: normalize, transpose via LDS, write split y A-image ----
    __syncthreads();                 // all waves done with K/V/P buffers
    float* Lt = (float*)smem;        // 128 rows x 66 f32 = 33792 B
    #pragma unroll
    for (int rb = 0; rb < 2; ++rb)
        #pragma unroll
        for (int r = 0; r < 4; ++r) {
            float l = lsum[rb][r];
            l += __shfl_xor(l, 1);
            l += __shfl_xor(l, 2);
            l += __shfl_xor(l, 4);
            l += __shfl_xor(l, 8);
            float inv = 1.0f / l;
            int row = 32*wv + 16*rb + 4*qd + r;
            Lt[row*66 + cl]      = accO[rb][0][r] * inv;
            Lt[row*66 + 16 + cl] = accO[rb][1][r] * inv;
            Lt[row*66 + 32 + cl] = accO[rb][2][r] * inv;
            Lt[row*66 + 48 + cl] = accO[rb][3][r] * inv;
        }
    __syncthreads();
    {
        const int r0   = tid >> 1;
        const int half = tid & 1;
        float f[32];
        #pragma unroll
        for (int u = 0; u < 16; ++u)
            *(float2*)(f + 2*u) = *(const float2*)(&Lt[r0*66 + half*32 + 2*u]);
        char* tile = Yimg + (size_t)((b*16 + qt)*16 + h) * 32768;
        #pragma unroll
        for (int cc = 0; cc < 4; ++cc) {
            uint4 h4, l4;
            split_pack8(f + 8*cc, h4, l4);
            int j    = half*4 + cc;
            int phys = j ^ (r0 & 7);
            *(uint4*)(tile + r0*128 + phys*16)         = h4;
            *(uint4*)(tile + 16384 + r0*128 + phys*16) = l4;
        }
    }
}

// ---------------------------------------------------------------------------
extern "C" void kernel_launch(void* const* d_in, const int* in_sizes, int n_in,
                              void* d_out, int out_size, void* d_ws, size_t ws_size,
                              hipStream_t stream) {
    const float* x    = (const float*)d_in[0];
    const float* cosp = (const float*)d_in[1];
    const float* sinp = (const float*)d_in[2];
    // d_in[3] = mask: unused by the reference computation
    const float* Wqkv = (const float*)d_in[4];
    const float* Wout = (const float*)d_in[5];
    float* out = (float*)d_out;

    char* ws = (char*)d_ws;
    float*  Qf    = (float*)(ws);                      // [ 0,16M)
    ushort* Kimg  = (ushort*)(ws + ((size_t)16<<20));  // [16,20M)
    ushort* Vimg  = (ushort*)(ws + ((size_t)20<<20));  // [20,24M)
    char*   Bo    = ws + ((size_t)24<<20);             // [24,28M)
    char*   Ximg  = ws + ((size_t)28<<20);             // [28,44M)  (dead after qkv-gemm)
    char*   Bq    = ws + ((size_t)44<<20);             // [44,50M)
    char*   Yimg  = ws + ((size_t)28<<20);             // [28,44M)  (over dead Ximg)

    // 1) input + weight images
    conv_xy<<<512, 256, 0, stream>>>(x, Ximg);
    conv_w<<<dim3(16, 12), 256, 0, stream>>>(Wqkv, FQKV, Bq);
    conv_w<<<dim3(16, 8), 256, 0, stream>>>(Wout, DEMBED, Bo);
    // 2) qkv projection + fused RoPE + K/V image build
    gemm_qkv_mfma<<<dim3(12, 32), 256, 0, stream>>>(Ximg, Bq, cosp, sinp,
                                                    Qf, Kimg, Vimg);
    // 3) attention -> writes y's A-image directly
    attn6<<<512, 256, 0, stream>>>(Qf, (const uint4*)Kimg, (const uint4*)Vimg,
                                   Yimg);
    // 4) out = y @ Wout
    gemm_out_mfma<<<dim3(8, 32), 256, 0, stream>>>(Yimg, Bo, out);
}